// Round 14
// baseline (572.771 us; speedup 1.0000x reference)
//
#include <hip/hip_runtime.h>
#include <hip/hip_fp16.h>
#include <math.h>

// Problem constants (fixed by the reference)
static constexpr int NN  = 50000;   // nodes
static constexpr int NE  = 600000;  // edges
static constexpr int HD  = 128;     // feature dim
static constexpr int NL  = 4;       // layers
static constexpr int NB  = 256;     // graphs
static constexpr int NM  = 200;     // molecule features
static constexpr int NO  = 12;      // out features
static constexpr int NMH = 32;      // molecular head width
static constexpr int CST = 64;      // fixed CSR stride (max degree; Poisson(12) -> P(>63) ~ 1e-30)

#define MAX4(ac, b) { (ac).x = fmaxf((ac).x,(b).x); (ac).y = fmaxf((ac).y,(b).y); (ac).z = fmaxf((ac).z,(b).z); (ac).w = fmaxf((ac).w,(b).w); }
#define ADD4(ac, b) { (ac).x += (b).x; (ac).y += (b).y; (ac).z += (b).z; (ac).w += (b).w; }

typedef short bfx8 __attribute__((ext_vector_type(8)));   // 8 bf16 in 4 VGPRs
typedef float f32x4 __attribute__((ext_vector_type(4)));  // MFMA accumulator

__device__ __forceinline__ unsigned short f2bf(float f) {   // RNE float->bf16
  unsigned int u = __float_as_uint(f);
  unsigned int r = (u + 0x7fffu + ((u >> 16) & 1u)) >> 16;
  return (unsigned short)r;
}
__device__ __forceinline__ float bflo(unsigned int p) { return __uint_as_float(p << 16); }
__device__ __forceinline__ float bfhi(unsigned int p) { return __uint_as_float(p & 0xffff0000u); }
__device__ __forceinline__ float h2f_hi(unsigned e) {       // fp16 bits in e[31:16] -> float
  return __half2float(__ushort_as_half((unsigned short)(e >> 16)));
}

// ---------------- degree histogram (int4-vectorized reads) ----------------
__global__ void k_hist(const int4* __restrict__ dst4, int* __restrict__ counts) {
  int i = blockIdx.x * blockDim.x + threadIdx.x;
  if (i < NE / 4) {
    int4 d = dst4[i];
    atomicAdd(&counts[d.x], 1);
    atomicAdd(&counts[d.y], 1);
    atomicAdd(&counts[d.z], 1);
    atomicAdd(&counts[d.w], 1);
  }
}

// ---------------- fused setup: x->bf16, W^T->bf16, graph offsets, dis + degree bins ----------------
static constexpr int NT_TOBF = NN * HD / 4;       // 1,600,000 float4-groups
static constexpr int NT_WT   = NL * HD * HD;      // 65,536
static constexpr int NT_GOFF = NT_TOBF + NT_WT;
static constexpr int NT_DIS  = NT_GOFF + NN;
static constexpr int NT_ALL  = NT_DIS + NN;

__global__ void k_setup(const float4* __restrict__ x4, ushort4* __restrict__ xbf4,
                        const float* __restrict__ Ws, unsigned short* __restrict__ wT,
                        const int* __restrict__ batch, int* __restrict__ goffs,
                        const int* __restrict__ counts, float* __restrict__ dis,
                        int* __restrict__ bins) {
  int i = blockIdx.x * blockDim.x + threadIdx.x;
  if (i < NT_TOBF) {
    float4 v = x4[i];
    xbf4[i] = make_ushort4(f2bf(v.x), f2bf(v.y), f2bf(v.z), f2bf(v.w));
  } else if (i < NT_GOFF) {
    int j = i - NT_TOBF;
    int l = j >> 14, rem = j & 16383, n = rem >> 7, k = rem & 127;
    wT[j] = f2bf(Ws[l * 16384 + k * 128 + n]);
  } else if (i < NT_DIS) {
    int j = i - NT_GOFF;   // node index
    int b = batch[j];
    if (j == 0) {
      for (int g = 0; g <= b; ++g) goffs[g] = 0;
    } else {
      int pb = batch[j - 1];
      for (int g = pb + 1; g <= b; ++g) goffs[g] = j;
    }
    if (j == NN - 1) goffs[NB] = NN;
  } else if (i < NT_ALL) {
    int j = i - NT_DIS;
    int d = counts[j];
    dis[j] = rsqrtf((float)(d + 1));
    atomicAdd(&bins[d > CST ? CST : d], 1);   // degree histogram for perm sort
  }
}

// ---------------- exclusive scan of 65 degree bins (tiny, 1 block) ----------------
__global__ void k_bscan(int* __restrict__ bins) {
  if (threadIdx.x == 0) {
    int run = 0;
    for (int d = 0; d <= CST; ++d) { int c = bins[d]; bins[d] = run; run += c; }
  }
}

// ---------------- fixed-stride CSR fill + degree-sorted perm scatter ----------------
// threads [0,NE): csr entry (4B) = fp16bits(dis[src])<<16 | src at slot d*CST + cursor
// threads [NE, NE+NN): perm[binoff[deg[n]]++] = n
__global__ void k_fill(const int* __restrict__ src, const int* __restrict__ dst,
                       const float* __restrict__ dis, int* __restrict__ cur,
                       unsigned* __restrict__ csr, const int* __restrict__ counts,
                       int* __restrict__ bins, int* __restrict__ perm) {
  int e = blockIdx.x * blockDim.x + threadIdx.x;
  if (e < NE) {
    int d = dst[e];
    int s = src[e];
    int p = atomicAdd(&cur[d], 1);
    unsigned hb = (unsigned)__half_as_ushort(__float2half(dis[s]));
    csr[d * CST + p] = (hb << 16) | (unsigned)s;
  } else if (e < NE + NN) {
    int n = e - NE;
    int d = counts[n]; if (d > CST) d = CST;
    int p = atomicAdd(&bins[d], 1);
    perm[p] = n;
  }
}

// ---------------- MFMA GEMM: C[NN,128] = A[NN,128] @ W, A/C bf16, W as WT[n][k] bf16 ----------------
__launch_bounds__(256)
__global__ void k_gemm_mfma(const unsigned short* __restrict__ A,
                            const unsigned short* __restrict__ WT,
                            unsigned short* __restrict__ C) {
  const int wave = threadIdx.x >> 6;
  const int lane = threadIdx.x & 63;
  const int m_base = blockIdx.x * 128 + wave * 32;
  const int lr = lane & 15;       // A row-in-frag / B col-in-frag
  const int kg = lane >> 4;       // k-subgroup: 8 contiguous k elems

  f32x4 acc[2][8];
#pragma unroll
  for (int mi = 0; mi < 2; ++mi)
#pragma unroll
    for (int nj = 0; nj < 8; ++nj) acc[mi][nj] = (f32x4){0.f, 0.f, 0.f, 0.f};

  int ra0 = m_base + lr;       if (ra0 > NN - 1) ra0 = NN - 1;
  int ra1 = m_base + 16 + lr;  if (ra1 > NN - 1) ra1 = NN - 1;

#pragma unroll
  for (int kb = 0; kb < 4; ++kb) {
    const int k0 = kb * 32 + kg * 8;
    bfx8 a0 = *(const bfx8*)&A[(size_t)ra0 * HD + k0];
    bfx8 a1 = *(const bfx8*)&A[(size_t)ra1 * HD + k0];
#pragma unroll
    for (int nj = 0; nj < 8; ++nj) {
      bfx8 b = *(const bfx8*)&WT[(nj * 16 + lr) * HD + k0];
      acc[0][nj] = __builtin_amdgcn_mfma_f32_16x16x32_bf16(a0, b, acc[0][nj], 0, 0, 0);
      acc[1][nj] = __builtin_amdgcn_mfma_f32_16x16x32_bf16(a1, b, acc[1][nj], 0, 0, 0);
    }
  }

  // C/D layout: col = lane&15, row = (lane>>4)*4 + reg   [m89 verified]
  const int col = lane & 15;
  const int rbase = (lane >> 4) * 4;
#pragma unroll
  for (int mi = 0; mi < 2; ++mi) {
#pragma unroll
    for (int r = 0; r < 4; ++r) {
      int row = m_base + mi * 16 + rbase + r;
      if (row < NN) {
#pragma unroll
        for (int nj = 0; nj < 8; ++nj) {
          C[(size_t)row * HD + nj * 16 + col] = f2bf(acc[mi][nj][r]);
        }
      }
    }
  }
}

// ---------------- aggregate + bias + relu + residual: 16 lanes/node, 16B gathers,
//                  degree-sorted node order (perm) -> near-uniform loop counts per wave ----------------
#define AGGE(e, p) { float nm = h2f_hi(e) * dn; \
    acc[0] += nm * bflo((p).x); acc[1] += nm * bfhi((p).x); \
    acc[2] += nm * bflo((p).y); acc[3] += nm * bfhi((p).y); \
    acc[4] += nm * bflo((p).z); acc[5] += nm * bfhi((p).z); \
    acc[6] += nm * bflo((p).w); acc[7] += nm * bfhi((p).w); }

__launch_bounds__(256)
__global__ void k_agg16(const unsigned short* __restrict__ xw, const float* __restrict__ dis,
                        const int* __restrict__ deg, const unsigned* __restrict__ csr,
                        const float* __restrict__ bias, const unsigned short* __restrict__ hinb,
                        unsigned short* __restrict__ houtb, const int* __restrict__ perm) {
  int slot = threadIdx.x >> 4;       // node slot 0..15
  int lane = threadIdx.x & 15;       // uint4 index within row (row = 16 uint4 = 256B)
  int i = blockIdx.x * 16 + slot;
  if (i >= NN) return;
  int n = perm[i];

  const uint4* xw4 = (const uint4*)xw;

  float dn = dis[n];
  float acc[8];
  {
    uint4 p = xw4[(size_t)n * 16 + lane];
    float sl = dn * dn;
    acc[0] = bflo(p.x) * sl; acc[1] = bfhi(p.x) * sl;
    acc[2] = bflo(p.y) * sl; acc[3] = bfhi(p.y) * sl;
    acc[4] = bflo(p.z) * sl; acc[5] = bfhi(p.z) * sl;
    acc[6] = bflo(p.w) * sl; acc[7] = bfhi(p.w) * sl;
  }

  int s0 = n * CST;
  int s1 = s0 + deg[n];
  int idx = s0;
  for (; idx + 8 <= s1; idx += 8) {
    unsigned e0 = csr[idx],     e1 = csr[idx + 1], e2 = csr[idx + 2], e3 = csr[idx + 3];
    unsigned e4 = csr[idx + 4], e5 = csr[idx + 5], e6 = csr[idx + 6], e7 = csr[idx + 7];
    uint4 p0 = xw4[(size_t)(e0 & 0xffffu) * 16 + lane];
    uint4 p1 = xw4[(size_t)(e1 & 0xffffu) * 16 + lane];
    uint4 p2 = xw4[(size_t)(e2 & 0xffffu) * 16 + lane];
    uint4 p3 = xw4[(size_t)(e3 & 0xffffu) * 16 + lane];
    uint4 p4 = xw4[(size_t)(e4 & 0xffffu) * 16 + lane];
    uint4 p5 = xw4[(size_t)(e5 & 0xffffu) * 16 + lane];
    uint4 p6 = xw4[(size_t)(e6 & 0xffffu) * 16 + lane];
    uint4 p7 = xw4[(size_t)(e7 & 0xffffu) * 16 + lane];
    AGGE(e0, p0); AGGE(e1, p1); AGGE(e2, p2); AGGE(e3, p3);
    AGGE(e4, p4); AGGE(e5, p5); AGGE(e6, p6); AGGE(e7, p7);
  }
  for (; idx + 4 <= s1; idx += 4) {
    unsigned e0 = csr[idx], e1 = csr[idx + 1], e2 = csr[idx + 2], e3 = csr[idx + 3];
    uint4 p0 = xw4[(size_t)(e0 & 0xffffu) * 16 + lane];
    uint4 p1 = xw4[(size_t)(e1 & 0xffffu) * 16 + lane];
    uint4 p2 = xw4[(size_t)(e2 & 0xffffu) * 16 + lane];
    uint4 p3 = xw4[(size_t)(e3 & 0xffffu) * 16 + lane];
    AGGE(e0, p0); AGGE(e1, p1); AGGE(e2, p2); AGGE(e3, p3);
  }
  for (; idx < s1; ++idx) {
    unsigned e0 = csr[idx];
    uint4 p0 = xw4[(size_t)(e0 & 0xffffu) * 16 + lane];
    AGGE(e0, p0);
  }

  float4 ba = *(const float4*)&bias[lane * 8];
  float4 bb = *(const float4*)&bias[lane * 8 + 4];
  uint4 hp = ((const uint4*)hinb)[(size_t)n * 16 + lane];
  float o0 = fmaxf(acc[0] + ba.x, 0.f) + bflo(hp.x);
  float o1 = fmaxf(acc[1] + ba.y, 0.f) + bfhi(hp.x);
  float o2 = fmaxf(acc[2] + ba.z, 0.f) + bflo(hp.y);
  float o3 = fmaxf(acc[3] + ba.w, 0.f) + bfhi(hp.y);
  float o4 = fmaxf(acc[4] + bb.x, 0.f) + bflo(hp.z);
  float o5 = fmaxf(acc[5] + bb.y, 0.f) + bfhi(hp.z);
  float o6 = fmaxf(acc[6] + bb.z, 0.f) + bflo(hp.w);
  float o7 = fmaxf(acc[7] + bb.w, 0.f) + bfhi(hp.w);
  uint4 ov;
  ov.x = (unsigned)f2bf(o0) | ((unsigned)f2bf(o1) << 16);
  ov.y = (unsigned)f2bf(o2) | ((unsigned)f2bf(o3) << 16);
  ov.z = (unsigned)f2bf(o4) | ((unsigned)f2bf(o5) << 16);
  ov.w = (unsigned)f2bf(o6) | ((unsigned)f2bf(o7) << 16);
  ((uint4*)houtb)[(size_t)n * 16 + lane] = ov;
}

// ---------------- fused pooling + head: one 1024-thread block per graph ----------------
__launch_bounds__(1024)
__global__ void k_poolhead(const unsigned short* __restrict__ hb, const int* __restrict__ goffs,
                           const float* __restrict__ mf,
                           const float* __restrict__ Wm, const float* __restrict__ bm,
                           const float* __restrict__ gamma, const float* __restrict__ beta,
                           const float* __restrict__ W1, const float* __restrict__ b1,
                           const float* __restrict__ W2, const float* __restrict__ b2,
                           float* __restrict__ out) {
  __shared__ float4 smax[32][32];   // [slot][lane]
  __shared__ float4 ssum[32][32];
  __shared__ float z[288];
  __shared__ float z1[128];
  int g = blockIdx.x;
  int slot = threadIdx.x >> 5;
  int lane = threadIdx.x & 31;
  int a = goffs[g], bnd = goffs[g + 1];
  const uint2* hb2 = (const uint2*)hb;

  float4 mx = make_float4(-INFINITY, -INFINITY, -INFINITY, -INFINITY);
  float4 sm = make_float4(0.f, 0.f, 0.f, 0.f);
  for (int i = a + slot; i < bnd; i += 32) {
    uint2 p = hb2[(size_t)i * 32 + lane];
    float4 v = make_float4(bflo(p.x), bfhi(p.x), bflo(p.y), bfhi(p.y));
    MAX4(mx, v);
    ADD4(sm, v);
  }
  smax[slot][lane] = mx;
  ssum[slot][lane] = sm;
  __syncthreads();
#pragma unroll
  for (int off = 16; off >= 1; off >>= 1) {
    if (slot < off) {
      float4 m2 = smax[slot + off][lane];
      float4 s2 = ssum[slot + off][lane];
      float4 m1 = smax[slot][lane];
      float4 s1 = ssum[slot][lane];
      MAX4(m1, m2);
      ADD4(s1, s2);
      smax[slot][lane] = m1;
      ssum[slot][lane] = s1;
    }
    __syncthreads();
  }
  if (slot == 0) {
    *(float4*)&z[lane * 4]       = smax[0][lane];
    *(float4*)&z[128 + lane * 4] = ssum[0][lane];
  }
  if (threadIdx.x < NMH) {
    int t = threadIdx.x;
    float acc = bm[t];
    for (int k = 0; k < NM; ++k) acc += mf[g * NM + k] * Wm[k * NMH + t];
    acc = acc * gamma[t] + beta[t];
    z[256 + t] = fmaxf(acc, 0.f);
  }
  __syncthreads();
  if (threadIdx.x < 128) {
    int t = threadIdx.x;
    float acc = b1[t];
    for (int k = 0; k < 288; ++k) acc += z[k] * W1[k * HD + t];
    z1[t] = fmaxf(acc, 0.f);
  }
  __syncthreads();
  if (threadIdx.x < NO) {
    int t = threadIdx.x;
    float a2 = b2[t];
    for (int k = 0; k < HD; ++k) a2 += z1[k] * W2[k * NO + t];
    out[g * NO + t] = a2;
  }
}

extern "C" void kernel_launch(void* const* d_in, const int* in_sizes, int n_in,
                              void* d_out, int out_size, void* d_ws, size_t ws_size,
                              hipStream_t stream) {
  const float* x     = (const float*)d_in[0];
  const int*   eidx  = (const int*)d_in[1];
  const int*   batch = (const int*)d_in[2];
  const float* mf    = (const float*)d_in[3];
  const float* Ws    = (const float*)d_in[4];
  const float* bs    = (const float*)d_in[5];
  const float* Wm    = (const float*)d_in[6];
  const float* bm    = (const float*)d_in[7];
  const float* gamma = (const float*)d_in[8];
  const float* beta  = (const float*)d_in[9];
  const float* W1    = (const float*)d_in[10];
  const float* b1    = (const float*)d_in[11];
  const float* W2    = (const float*)d_in[12];
  const float* b2    = (const float*)d_in[13];
  float* out = (float*)d_out;

  const int* src = eidx;
  const int* dst = eidx + NE;

  // workspace carve-out
  char* w = (char*)d_ws;
  size_t off = 0;
  auto alloc = [&](size_t bytes) -> void* {
    void* p = w + off;
    off += (bytes + 255) & ~(size_t)255;
    return p;
  };
  float* dis    = (float*)alloc((size_t)NN * 4);
  unsigned short* xw  = (unsigned short*)alloc((size_t)NN * HD * 2);  // bf16 GEMM out
  unsigned short* xbf = (unsigned short*)alloc((size_t)NN * HD * 2);  // bf16 copy of x
  unsigned short* hbf = (unsigned short*)alloc((size_t)NN * HD * 2);  // bf16 h state
  unsigned short* wT  = (unsigned short*)alloc((size_t)NL * HD * HD * 2);
  int* counts   = (int*)alloc((size_t)NN * 4);        // degree
  int* cur      = (int*)alloc((size_t)NN * 4);        // fill cursor (adjacent)
  int* bins     = (int*)alloc(128 * 4);               // degree bins (adjacent)
  unsigned* csr = (unsigned*)alloc((size_t)NN * CST * 4);
  int* perm     = (int*)alloc((size_t)NN * 4);
  int* goffs    = (int*)alloc((size_t)(NB + 1) * 4);
  (void)ws_size;

  // one memset covers counts + cur + bins (adjacent carve-outs)
  size_t zspan = (size_t)((char*)(bins + 128) - (char*)counts);
  hipMemsetAsync(counts, 0, zspan, stream);

  k_hist<<<(NE / 4 + 255) / 256, 256, 0, stream>>>((const int4*)dst, counts);
  k_setup<<<(NT_ALL + 255) / 256, 256, 0, stream>>>((const float4*)x, (ushort4*)xbf,
                                                    Ws, wT, batch, goffs, counts, dis, bins);
  k_bscan<<<1, 64, 0, stream>>>(bins);
  k_fill<<<(NE + NN + 255) / 256, 256, 0, stream>>>(src, dst, dis, cur, csr, counts, bins, perm);

  for (int l = 0; l < NL; ++l) {
    const unsigned short* gin_bf = (l == 0) ? xbf : hbf;
    k_gemm_mfma<<<(NN + 127) / 128, 256, 0, stream>>>(gin_bf, wT + (size_t)l * HD * HD, xw);
    k_agg16<<<(NN + 15) / 16, 256, 0, stream>>>(xw, dis, counts, csr, bs + (size_t)l * HD,
                                                gin_bf, hbf, perm);
  }

  k_poolhead<<<NB, 1024, 0, stream>>>(hbf, goffs, mf, Wm, bm, gamma, beta, W1, b1, W2, b2, out);
}

// Round 15
// 272.000 us; speedup vs baseline: 2.1058x; 2.1058x over previous
//
#include <hip/hip_runtime.h>
#include <hip/hip_fp16.h>
#include <math.h>

// Problem constants (fixed by the reference)
static constexpr int NN  = 50000;   // nodes
static constexpr int NE  = 600000;  // edges
static constexpr int HD  = 128;     // feature dim
static constexpr int NL  = 4;       // layers
static constexpr int NB  = 256;     // graphs
static constexpr int NM  = 200;     // molecule features
static constexpr int NO  = 12;      // out features
static constexpr int NMH = 32;      // molecular head width
static constexpr int CST = 64;      // fixed CSR stride (max degree; Poisson(12) -> P(>63) ~ 1e-30)

#define MAX4(ac, b) { (ac).x = fmaxf((ac).x,(b).x); (ac).y = fmaxf((ac).y,(b).y); (ac).z = fmaxf((ac).z,(b).z); (ac).w = fmaxf((ac).w,(b).w); }
#define ADD4(ac, b) { (ac).x += (b).x; (ac).y += (b).y; (ac).z += (b).z; (ac).w += (b).w; }

typedef short bfx8 __attribute__((ext_vector_type(8)));   // 8 bf16 in 4 VGPRs
typedef float f32x4 __attribute__((ext_vector_type(4)));  // MFMA accumulator

__device__ __forceinline__ unsigned short f2bf(float f) {   // RNE float->bf16
  unsigned int u = __float_as_uint(f);
  unsigned int r = (u + 0x7fffu + ((u >> 16) & 1u)) >> 16;
  return (unsigned short)r;
}
__device__ __forceinline__ float bflo(unsigned int p) { return __uint_as_float(p << 16); }
__device__ __forceinline__ float bfhi(unsigned int p) { return __uint_as_float(p & 0xffff0000u); }
__device__ __forceinline__ float h2f_hi(unsigned e) {       // fp16 bits in e[31:16] -> float
  return __half2float(__ushort_as_half((unsigned short)(e >> 16)));
}

// ---------------- degree histogram (int4-vectorized reads) ----------------
__global__ void k_hist(const int4* __restrict__ dst4, int* __restrict__ counts) {
  int i = blockIdx.x * blockDim.x + threadIdx.x;
  if (i < NE / 4) {
    int4 d = dst4[i];
    atomicAdd(&counts[d.x], 1);
    atomicAdd(&counts[d.y], 1);
    atomicAdd(&counts[d.z], 1);
    atomicAdd(&counts[d.w], 1);
  }
}

// ---------------- fused setup: x->bf16, W^T->bf16, graph offsets, dis ----------------
static constexpr int NT_TOBF = NN * HD / 4;       // 1,600,000 float4-groups
static constexpr int NT_WT   = NL * HD * HD;      // 65,536
static constexpr int NT_GOFF = NT_TOBF + NT_WT;
static constexpr int NT_DIS  = NT_GOFF + NN;
static constexpr int NT_ALL  = NT_DIS + NN;

__global__ void k_setup(const float4* __restrict__ x4, ushort4* __restrict__ xbf4,
                        const float* __restrict__ Ws, unsigned short* __restrict__ wT,
                        const int* __restrict__ batch, int* __restrict__ goffs,
                        const int* __restrict__ counts, float* __restrict__ dis) {
  int i = blockIdx.x * blockDim.x + threadIdx.x;
  if (i < NT_TOBF) {
    float4 v = x4[i];
    xbf4[i] = make_ushort4(f2bf(v.x), f2bf(v.y), f2bf(v.z), f2bf(v.w));
  } else if (i < NT_GOFF) {
    int j = i - NT_TOBF;
    int l = j >> 14, rem = j & 16383, n = rem >> 7, k = rem & 127;
    wT[j] = f2bf(Ws[l * 16384 + k * 128 + n]);
  } else if (i < NT_DIS) {
    int j = i - NT_GOFF;   // node index
    int b = batch[j];
    if (j == 0) {
      for (int g = 0; g <= b; ++g) goffs[g] = 0;
    } else {
      int pb = batch[j - 1];
      for (int g = pb + 1; g <= b; ++g) goffs[g] = j;
    }
    if (j == NN - 1) goffs[NB] = NN;
  } else if (i < NT_ALL) {
    int j = i - NT_DIS;
    dis[j] = rsqrtf((float)(counts[j] + 1));
  }
}

// ---------------- fixed-stride CSR fill ----------------
// csr entry (4B) = fp16bits(dis[src])<<16 | src; slot d*CST + atomicAdd(cur[d])
__global__ void k_fill(const int* __restrict__ src, const int* __restrict__ dst,
                       const float* __restrict__ dis, int* __restrict__ cur,
                       unsigned* __restrict__ csr) {
  int e = blockIdx.x * blockDim.x + threadIdx.x;
  if (e < NE) {
    int d = dst[e];
    int s = src[e];
    int p = atomicAdd(&cur[d], 1);
    unsigned hb = (unsigned)__half_as_ushort(__float2half(dis[s]));
    csr[d * CST + p] = (hb << 16) | (unsigned)s;
  }
}

// ---------------- MFMA GEMM: C[NN,128] = A[NN,128] @ W, A/C bf16, W as WT[n][k] bf16 ----------------
__launch_bounds__(256)
__global__ void k_gemm_mfma(const unsigned short* __restrict__ A,
                            const unsigned short* __restrict__ WT,
                            unsigned short* __restrict__ C) {
  const int wave = threadIdx.x >> 6;
  const int lane = threadIdx.x & 63;
  const int m_base = blockIdx.x * 128 + wave * 32;
  const int lr = lane & 15;       // A row-in-frag / B col-in-frag
  const int kg = lane >> 4;       // k-subgroup: 8 contiguous k elems

  f32x4 acc[2][8];
#pragma unroll
  for (int mi = 0; mi < 2; ++mi)
#pragma unroll
    for (int nj = 0; nj < 8; ++nj) acc[mi][nj] = (f32x4){0.f, 0.f, 0.f, 0.f};

  int ra0 = m_base + lr;       if (ra0 > NN - 1) ra0 = NN - 1;
  int ra1 = m_base + 16 + lr;  if (ra1 > NN - 1) ra1 = NN - 1;

#pragma unroll
  for (int kb = 0; kb < 4; ++kb) {
    const int k0 = kb * 32 + kg * 8;
    bfx8 a0 = *(const bfx8*)&A[(size_t)ra0 * HD + k0];
    bfx8 a1 = *(const bfx8*)&A[(size_t)ra1 * HD + k0];
#pragma unroll
    for (int nj = 0; nj < 8; ++nj) {
      bfx8 b = *(const bfx8*)&WT[(nj * 16 + lr) * HD + k0];
      acc[0][nj] = __builtin_amdgcn_mfma_f32_16x16x32_bf16(a0, b, acc[0][nj], 0, 0, 0);
      acc[1][nj] = __builtin_amdgcn_mfma_f32_16x16x32_bf16(a1, b, acc[1][nj], 0, 0, 0);
    }
  }

  // C/D layout: col = lane&15, row = (lane>>4)*4 + reg   [m89 verified]
  const int col = lane & 15;
  const int rbase = (lane >> 4) * 4;
#pragma unroll
  for (int mi = 0; mi < 2; ++mi) {
#pragma unroll
    for (int r = 0; r < 4; ++r) {
      int row = m_base + mi * 16 + rbase + r;
      if (row < NN) {
#pragma unroll
        for (int nj = 0; nj < 8; ++nj) {
          C[(size_t)row * HD + nj * 16 + col] = f2bf(acc[mi][nj][r]);
        }
      }
    }
  }
}

// ---------------- aggregate + bias + relu + residual: 16 lanes/node, 16B gathers ----------------
#define AGGE(e, p) { float nm = h2f_hi(e) * dn; \
    acc[0] += nm * bflo((p).x); acc[1] += nm * bfhi((p).x); \
    acc[2] += nm * bflo((p).y); acc[3] += nm * bfhi((p).y); \
    acc[4] += nm * bflo((p).z); acc[5] += nm * bfhi((p).z); \
    acc[6] += nm * bflo((p).w); acc[7] += nm * bfhi((p).w); }

__launch_bounds__(256)
__global__ void k_agg16(const unsigned short* __restrict__ xw, const float* __restrict__ dis,
                        const int* __restrict__ deg, const unsigned* __restrict__ csr,
                        const float* __restrict__ bias, const unsigned short* __restrict__ hinb,
                        unsigned short* __restrict__ houtb) {
  int slot = threadIdx.x >> 4;       // node slot 0..15
  int lane = threadIdx.x & 15;       // uint4 index within row (row = 16 uint4 = 256B)
  int n = blockIdx.x * 16 + slot;
  if (n >= NN) return;

  const uint4* xw4 = (const uint4*)xw;

  float dn = dis[n];
  float acc[8];
  {
    uint4 p = xw4[(size_t)n * 16 + lane];
    float sl = dn * dn;
    acc[0] = bflo(p.x) * sl; acc[1] = bfhi(p.x) * sl;
    acc[2] = bflo(p.y) * sl; acc[3] = bfhi(p.y) * sl;
    acc[4] = bflo(p.z) * sl; acc[5] = bfhi(p.z) * sl;
    acc[6] = bflo(p.w) * sl; acc[7] = bfhi(p.w) * sl;
  }

  int s0 = n * CST;
  int s1 = s0 + deg[n];
  int idx = s0;
  for (; idx + 8 <= s1; idx += 8) {
    unsigned e0 = csr[idx],     e1 = csr[idx + 1], e2 = csr[idx + 2], e3 = csr[idx + 3];
    unsigned e4 = csr[idx + 4], e5 = csr[idx + 5], e6 = csr[idx + 6], e7 = csr[idx + 7];
    uint4 p0 = xw4[(size_t)(e0 & 0xffffu) * 16 + lane];
    uint4 p1 = xw4[(size_t)(e1 & 0xffffu) * 16 + lane];
    uint4 p2 = xw4[(size_t)(e2 & 0xffffu) * 16 + lane];
    uint4 p3 = xw4[(size_t)(e3 & 0xffffu) * 16 + lane];
    uint4 p4 = xw4[(size_t)(e4 & 0xffffu) * 16 + lane];
    uint4 p5 = xw4[(size_t)(e5 & 0xffffu) * 16 + lane];
    uint4 p6 = xw4[(size_t)(e6 & 0xffffu) * 16 + lane];
    uint4 p7 = xw4[(size_t)(e7 & 0xffffu) * 16 + lane];
    AGGE(e0, p0); AGGE(e1, p1); AGGE(e2, p2); AGGE(e3, p3);
    AGGE(e4, p4); AGGE(e5, p5); AGGE(e6, p6); AGGE(e7, p7);
  }
  for (; idx + 4 <= s1; idx += 4) {
    unsigned e0 = csr[idx], e1 = csr[idx + 1], e2 = csr[idx + 2], e3 = csr[idx + 3];
    uint4 p0 = xw4[(size_t)(e0 & 0xffffu) * 16 + lane];
    uint4 p1 = xw4[(size_t)(e1 & 0xffffu) * 16 + lane];
    uint4 p2 = xw4[(size_t)(e2 & 0xffffu) * 16 + lane];
    uint4 p3 = xw4[(size_t)(e3 & 0xffffu) * 16 + lane];
    AGGE(e0, p0); AGGE(e1, p1); AGGE(e2, p2); AGGE(e3, p3);
  }
  for (; idx < s1; ++idx) {
    unsigned e0 = csr[idx];
    uint4 p0 = xw4[(size_t)(e0 & 0xffffu) * 16 + lane];
    AGGE(e0, p0);
  }

  float4 ba = *(const float4*)&bias[lane * 8];
  float4 bb = *(const float4*)&bias[lane * 8 + 4];
  uint4 hp = ((const uint4*)hinb)[(size_t)n * 16 + lane];
  float o0 = fmaxf(acc[0] + ba.x, 0.f) + bflo(hp.x);
  float o1 = fmaxf(acc[1] + ba.y, 0.f) + bfhi(hp.x);
  float o2 = fmaxf(acc[2] + ba.z, 0.f) + bflo(hp.y);
  float o3 = fmaxf(acc[3] + ba.w, 0.f) + bfhi(hp.y);
  float o4 = fmaxf(acc[4] + bb.x, 0.f) + bflo(hp.z);
  float o5 = fmaxf(acc[5] + bb.y, 0.f) + bfhi(hp.z);
  float o6 = fmaxf(acc[6] + bb.z, 0.f) + bflo(hp.w);
  float o7 = fmaxf(acc[7] + bb.w, 0.f) + bfhi(hp.w);
  uint4 ov;
  ov.x = (unsigned)f2bf(o0) | ((unsigned)f2bf(o1) << 16);
  ov.y = (unsigned)f2bf(o2) | ((unsigned)f2bf(o3) << 16);
  ov.z = (unsigned)f2bf(o4) | ((unsigned)f2bf(o5) << 16);
  ov.w = (unsigned)f2bf(o6) | ((unsigned)f2bf(o7) << 16);
  ((uint4*)houtb)[(size_t)n * 16 + lane] = ov;
}

// ---------------- fused pooling + head: one 1024-thread block per graph ----------------
__launch_bounds__(1024)
__global__ void k_poolhead(const unsigned short* __restrict__ hb, const int* __restrict__ goffs,
                           const float* __restrict__ mf,
                           const float* __restrict__ Wm, const float* __restrict__ bm,
                           const float* __restrict__ gamma, const float* __restrict__ beta,
                           const float* __restrict__ W1, const float* __restrict__ b1,
                           const float* __restrict__ W2, const float* __restrict__ b2,
                           float* __restrict__ out) {
  __shared__ float4 smax[32][32];   // [slot][lane]
  __shared__ float4 ssum[32][32];
  __shared__ float z[288];
  __shared__ float z1[128];
  int g = blockIdx.x;
  int slot = threadIdx.x >> 5;
  int lane = threadIdx.x & 31;
  int a = goffs[g], bnd = goffs[g + 1];
  const uint2* hb2 = (const uint2*)hb;

  float4 mx = make_float4(-INFINITY, -INFINITY, -INFINITY, -INFINITY);
  float4 sm = make_float4(0.f, 0.f, 0.f, 0.f);
  for (int i = a + slot; i < bnd; i += 32) {
    uint2 p = hb2[(size_t)i * 32 + lane];
    float4 v = make_float4(bflo(p.x), bfhi(p.x), bflo(p.y), bfhi(p.y));
    MAX4(mx, v);
    ADD4(sm, v);
  }
  smax[slot][lane] = mx;
  ssum[slot][lane] = sm;
  __syncthreads();
#pragma unroll
  for (int off = 16; off >= 1; off >>= 1) {
    if (slot < off) {
      float4 m2 = smax[slot + off][lane];
      float4 s2 = ssum[slot + off][lane];
      float4 m1 = smax[slot][lane];
      float4 s1 = ssum[slot][lane];
      MAX4(m1, m2);
      ADD4(s1, s2);
      smax[slot][lane] = m1;
      ssum[slot][lane] = s1;
    }
    __syncthreads();
  }
  if (slot == 0) {
    *(float4*)&z[lane * 4]       = smax[0][lane];
    *(float4*)&z[128 + lane * 4] = ssum[0][lane];
  }
  if (threadIdx.x < NMH) {
    int t = threadIdx.x;
    float acc = bm[t];
    for (int k = 0; k < NM; ++k) acc += mf[g * NM + k] * Wm[k * NMH + t];
    acc = acc * gamma[t] + beta[t];
    z[256 + t] = fmaxf(acc, 0.f);
  }
  __syncthreads();
  if (threadIdx.x < 128) {
    int t = threadIdx.x;
    float acc = b1[t];
    for (int k = 0; k < 288; ++k) acc += z[k] * W1[k * HD + t];
    z1[t] = fmaxf(acc, 0.f);
  }
  __syncthreads();
  if (threadIdx.x < NO) {
    int t = threadIdx.x;
    float a2 = b2[t];
    for (int k = 0; k < HD; ++k) a2 += z1[k] * W2[k * NO + t];
    out[g * NO + t] = a2;
  }
}

extern "C" void kernel_launch(void* const* d_in, const int* in_sizes, int n_in,
                              void* d_out, int out_size, void* d_ws, size_t ws_size,
                              hipStream_t stream) {
  const float* x     = (const float*)d_in[0];
  const int*   eidx  = (const int*)d_in[1];
  const int*   batch = (const int*)d_in[2];
  const float* mf    = (const float*)d_in[3];
  const float* Ws    = (const float*)d_in[4];
  const float* bs    = (const float*)d_in[5];
  const float* Wm    = (const float*)d_in[6];
  const float* bm    = (const float*)d_in[7];
  const float* gamma = (const float*)d_in[8];
  const float* beta  = (const float*)d_in[9];
  const float* W1    = (const float*)d_in[10];
  const float* b1    = (const float*)d_in[11];
  const float* W2    = (const float*)d_in[12];
  const float* b2    = (const float*)d_in[13];
  float* out = (float*)d_out;

  const int* src = eidx;
  const int* dst = eidx + NE;

  // workspace carve-out
  char* w = (char*)d_ws;
  size_t off = 0;
  auto alloc = [&](size_t bytes) -> void* {
    void* p = w + off;
    off += (bytes + 255) & ~(size_t)255;
    return p;
  };
  float* dis    = (float*)alloc((size_t)NN * 4);
  unsigned short* xw  = (unsigned short*)alloc((size_t)NN * HD * 2);  // bf16 GEMM out
  unsigned short* xbf = (unsigned short*)alloc((size_t)NN * HD * 2);  // bf16 copy of x
  unsigned short* hbf = (unsigned short*)alloc((size_t)NN * HD * 2);  // bf16 h state
  unsigned short* wT  = (unsigned short*)alloc((size_t)NL * HD * HD * 2);
  int* counts   = (int*)alloc((size_t)NN * 4);        // degree
  int* cur      = (int*)alloc((size_t)NN * 4);        // fill cursor (adjacent to counts)
  unsigned* csr = (unsigned*)alloc((size_t)NN * CST * 4);
  int* goffs    = (int*)alloc((size_t)(NB + 1) * 4);
  (void)ws_size;

  // one memset covers counts + cur (adjacent carve-outs)
  size_t zspan = (size_t)((char*)(cur + NN) - (char*)counts);
  hipMemsetAsync(counts, 0, zspan, stream);

  k_hist<<<(NE / 4 + 255) / 256, 256, 0, stream>>>((const int4*)dst, counts);
  k_setup<<<(NT_ALL + 255) / 256, 256, 0, stream>>>((const float4*)x, (ushort4*)xbf,
                                                    Ws, wT, batch, goffs, counts, dis);
  k_fill<<<(NE + 255) / 256, 256, 0, stream>>>(src, dst, dis, cur, csr);

  for (int l = 0; l < NL; ++l) {
    const unsigned short* gin_bf = (l == 0) ? xbf : hbf;
    k_gemm_mfma<<<(NN + 127) / 128, 256, 0, stream>>>(gin_bf, wT + (size_t)l * HD * HD, xw);
    k_agg16<<<(NN + 15) / 16, 256, 0, stream>>>(xw, dis, counts, csr, bs + (size_t)l * HD, gin_bf, hbf);
  }

  k_poolhead<<<NB, 1024, 0, stream>>>(hbf, goffs, mf, Wm, bm, gamma, beta, W1, b1, W2, b2, out);
}

// Round 16
// 269.455 us; speedup vs baseline: 2.1257x; 1.0094x over previous
//
#include <hip/hip_runtime.h>
#include <hip/hip_fp16.h>
#include <math.h>

// Problem constants (fixed by the reference)
static constexpr int NN  = 50000;   // nodes
static constexpr int NE  = 600000;  // edges
static constexpr int HD  = 128;     // feature dim
static constexpr int NL  = 4;       // layers
static constexpr int NB  = 256;     // graphs
static constexpr int NM  = 200;     // molecule features
static constexpr int NO  = 12;      // out features
static constexpr int NMH = 32;      // molecular head width
static constexpr int CST = 64;      // fixed CSR stride (max degree; Poisson(12) -> P(>63) ~ 1e-30)

#define MAX4(ac, b) { (ac).x = fmaxf((ac).x,(b).x); (ac).y = fmaxf((ac).y,(b).y); (ac).z = fmaxf((ac).z,(b).z); (ac).w = fmaxf((ac).w,(b).w); }
#define ADD4(ac, b) { (ac).x += (b).x; (ac).y += (b).y; (ac).z += (b).z; (ac).w += (b).w; }

typedef short bfx8 __attribute__((ext_vector_type(8)));   // 8 bf16 in 4 VGPRs
typedef float f32x4 __attribute__((ext_vector_type(4)));  // MFMA accumulator

__device__ __forceinline__ unsigned short f2bf(float f) {   // RNE float->bf16
  unsigned int u = __float_as_uint(f);
  unsigned int r = (u + 0x7fffu + ((u >> 16) & 1u)) >> 16;
  return (unsigned short)r;
}
__device__ __forceinline__ float bflo(unsigned int p) { return __uint_as_float(p << 16); }
__device__ __forceinline__ float bfhi(unsigned int p) { return __uint_as_float(p & 0xffff0000u); }
__device__ __forceinline__ float h2f_hi(unsigned e) {       // fp16 bits in e[31:16] -> float
  return __half2float(__ushort_as_half((unsigned short)(e >> 16)));
}

// ---------------- degree histogram (int4-vectorized reads) ----------------
__global__ void k_hist(const int4* __restrict__ dst4, int* __restrict__ counts) {
  int i = blockIdx.x * blockDim.x + threadIdx.x;
  if (i < NE / 4) {
    int4 d = dst4[i];
    atomicAdd(&counts[d.x], 1);
    atomicAdd(&counts[d.y], 1);
    atomicAdd(&counts[d.z], 1);
    atomicAdd(&counts[d.w], 1);
  }
}

// ---------------- fused setup: x->bf16, W^T->bf16, graph offsets, dis ----------------
static constexpr int NT_TOBF = NN * HD / 4;       // 1,600,000 float4-groups
static constexpr int NT_WT   = NL * HD * HD;      // 65,536
static constexpr int NT_GOFF = NT_TOBF + NT_WT;
static constexpr int NT_DIS  = NT_GOFF + NN;
static constexpr int NT_ALL  = NT_DIS + NN;

__global__ void k_setup(const float4* __restrict__ x4, ushort4* __restrict__ xbf4,
                        const float* __restrict__ Ws, unsigned short* __restrict__ wT,
                        const int* __restrict__ batch, int* __restrict__ goffs,
                        const int* __restrict__ counts, float* __restrict__ dis) {
  int i = blockIdx.x * blockDim.x + threadIdx.x;
  if (i < NT_TOBF) {
    float4 v = x4[i];
    xbf4[i] = make_ushort4(f2bf(v.x), f2bf(v.y), f2bf(v.z), f2bf(v.w));
  } else if (i < NT_GOFF) {
    int j = i - NT_TOBF;
    int l = j >> 14, rem = j & 16383, n = rem >> 7, k = rem & 127;
    wT[j] = f2bf(Ws[l * 16384 + k * 128 + n]);
  } else if (i < NT_DIS) {
    int j = i - NT_GOFF;   // node index
    int b = batch[j];
    if (j == 0) {
      for (int g = 0; g <= b; ++g) goffs[g] = 0;
    } else {
      int pb = batch[j - 1];
      for (int g = pb + 1; g <= b; ++g) goffs[g] = j;
    }
    if (j == NN - 1) goffs[NB] = NN;
  } else if (i < NT_ALL) {
    int j = i - NT_DIS;
    dis[j] = rsqrtf((float)(counts[j] + 1));
  }
}

// ---------------- fixed-stride CSR fill ----------------
// csr entry (4B) = fp16bits(dis[src])<<16 | src; slot d*CST + atomicAdd(cur[d])
__global__ void k_fill(const int* __restrict__ src, const int* __restrict__ dst,
                       const float* __restrict__ dis, int* __restrict__ cur,
                       unsigned* __restrict__ csr) {
  int e = blockIdx.x * blockDim.x + threadIdx.x;
  if (e < NE) {
    int d = dst[e];
    int s = src[e];
    int p = atomicAdd(&cur[d], 1);
    unsigned hb = (unsigned)__half_as_ushort(__float2half(dis[s]));
    csr[d * CST + p] = (hb << 16) | (unsigned)s;
  }
}

// ---------------- MFMA GEMM: C[NN,128] = A[NN,128] @ W, A/C bf16, W as WT[n][k] bf16 ----------------
__launch_bounds__(256)
__global__ void k_gemm_mfma(const unsigned short* __restrict__ A,
                            const unsigned short* __restrict__ WT,
                            unsigned short* __restrict__ C) {
  const int wave = threadIdx.x >> 6;
  const int lane = threadIdx.x & 63;
  const int m_base = blockIdx.x * 128 + wave * 32;
  const int lr = lane & 15;       // A row-in-frag / B col-in-frag
  const int kg = lane >> 4;       // k-subgroup: 8 contiguous k elems

  f32x4 acc[2][8];
#pragma unroll
  for (int mi = 0; mi < 2; ++mi)
#pragma unroll
    for (int nj = 0; nj < 8; ++nj) acc[mi][nj] = (f32x4){0.f, 0.f, 0.f, 0.f};

  int ra0 = m_base + lr;       if (ra0 > NN - 1) ra0 = NN - 1;
  int ra1 = m_base + 16 + lr;  if (ra1 > NN - 1) ra1 = NN - 1;

#pragma unroll
  for (int kb = 0; kb < 4; ++kb) {
    const int k0 = kb * 32 + kg * 8;
    bfx8 a0 = *(const bfx8*)&A[(size_t)ra0 * HD + k0];
    bfx8 a1 = *(const bfx8*)&A[(size_t)ra1 * HD + k0];
#pragma unroll
    for (int nj = 0; nj < 8; ++nj) {
      bfx8 b = *(const bfx8*)&WT[(nj * 16 + lr) * HD + k0];
      acc[0][nj] = __builtin_amdgcn_mfma_f32_16x16x32_bf16(a0, b, acc[0][nj], 0, 0, 0);
      acc[1][nj] = __builtin_amdgcn_mfma_f32_16x16x32_bf16(a1, b, acc[1][nj], 0, 0, 0);
    }
  }

  // C/D layout: col = lane&15, row = (lane>>4)*4 + reg   [m89 verified]
  const int col = lane & 15;
  const int rbase = (lane >> 4) * 4;
#pragma unroll
  for (int mi = 0; mi < 2; ++mi) {
#pragma unroll
    for (int r = 0; r < 4; ++r) {
      int row = m_base + mi * 16 + rbase + r;
      if (row < NN) {
#pragma unroll
        for (int nj = 0; nj < 8; ++nj) {
          C[(size_t)row * HD + nj * 16 + col] = f2bf(acc[mi][nj][r]);
        }
      }
    }
  }
}

// ---------------- aggregate + bias + relu + residual: 16 lanes/node, 16B gathers,
//                  16-entry CSR prefetch -> up to 16 gathers in flight back-to-back ----------------
#define AGGE(e, p) { float nm = h2f_hi(e) * dn; \
    acc[0] += nm * bflo((p).x); acc[1] += nm * bfhi((p).x); \
    acc[2] += nm * bflo((p).y); acc[3] += nm * bfhi((p).y); \
    acc[4] += nm * bflo((p).z); acc[5] += nm * bfhi((p).z); \
    acc[6] += nm * bflo((p).w); acc[7] += nm * bfhi((p).w); }

__launch_bounds__(256)
__global__ void k_agg16(const unsigned short* __restrict__ xw, const float* __restrict__ dis,
                        const int* __restrict__ deg, const unsigned* __restrict__ csr,
                        const float* __restrict__ bias, const unsigned short* __restrict__ hinb,
                        unsigned short* __restrict__ houtb) {
  int slot = threadIdx.x >> 4;       // node slot 0..15
  int lane = threadIdx.x & 15;       // uint4 index within row (row = 16 uint4 = 256B)
  int n = blockIdx.x * 16 + slot;
  if (n >= NN) return;

  const uint4* xw4  = (const uint4*)xw;
  const uint4* csr4 = (const uint4*)csr;   // node n's slots: csr4[n*16 + 0..15]

  float dn = dis[n];
  float acc[8];
  {
    uint4 p = xw4[(size_t)n * 16 + lane];
    float sl = dn * dn;
    acc[0] = bflo(p.x) * sl; acc[1] = bfhi(p.x) * sl;
    acc[2] = bflo(p.y) * sl; acc[3] = bfhi(p.y) * sl;
    acc[4] = bflo(p.z) * sl; acc[5] = bfhi(p.z) * sl;
    acc[6] = bflo(p.w) * sl; acc[7] = bfhi(p.w) * sl;
  }

  const int d = deg[n];

  // Prefetch first 16 CSR entries (4 independent contiguous uint4 loads),
  // then issue up to 16 gathers back-to-back, predicated on i<d.
  // Slack slots hold garbage but are never used (i<d guard).
  uint4 c0 = csr4[(size_t)n * 16 + 0];
  uint4 c1 = csr4[(size_t)n * 16 + 1];
  uint4 c2 = csr4[(size_t)n * 16 + 2];
  uint4 c3 = csr4[(size_t)n * 16 + 3];
  const unsigned ce[16] = {c0.x, c0.y, c0.z, c0.w, c1.x, c1.y, c1.z, c1.w,
                           c2.x, c2.y, c2.z, c2.w, c3.x, c3.y, c3.z, c3.w};
#pragma unroll
  for (int i = 0; i < 16; ++i) {
    if (i < d) {
      unsigned e0 = ce[i];
      uint4 p0 = xw4[(size_t)(e0 & 0xffffu) * 16 + lane];
      AGGE(e0, p0);
    }
  }

  // tail for deg > 16
  int idx = n * CST + 16;
  int s1 = n * CST + d;
  for (; idx + 4 <= s1; idx += 4) {
    unsigned e0 = csr[idx], e1 = csr[idx + 1], e2 = csr[idx + 2], e3 = csr[idx + 3];
    uint4 p0 = xw4[(size_t)(e0 & 0xffffu) * 16 + lane];
    uint4 p1 = xw4[(size_t)(e1 & 0xffffu) * 16 + lane];
    uint4 p2 = xw4[(size_t)(e2 & 0xffffu) * 16 + lane];
    uint4 p3 = xw4[(size_t)(e3 & 0xffffu) * 16 + lane];
    AGGE(e0, p0); AGGE(e1, p1); AGGE(e2, p2); AGGE(e3, p3);
  }
  for (; idx < s1; ++idx) {
    unsigned e0 = csr[idx];
    uint4 p0 = xw4[(size_t)(e0 & 0xffffu) * 16 + lane];
    AGGE(e0, p0);
  }

  float4 ba = *(const float4*)&bias[lane * 8];
  float4 bb = *(const float4*)&bias[lane * 8 + 4];
  uint4 hp = ((const uint4*)hinb)[(size_t)n * 16 + lane];
  float o0 = fmaxf(acc[0] + ba.x, 0.f) + bflo(hp.x);
  float o1 = fmaxf(acc[1] + ba.y, 0.f) + bfhi(hp.x);
  float o2 = fmaxf(acc[2] + ba.z, 0.f) + bflo(hp.y);
  float o3 = fmaxf(acc[3] + ba.w, 0.f) + bfhi(hp.y);
  float o4 = fmaxf(acc[4] + bb.x, 0.f) + bflo(hp.z);
  float o5 = fmaxf(acc[5] + bb.y, 0.f) + bfhi(hp.z);
  float o6 = fmaxf(acc[6] + bb.z, 0.f) + bflo(hp.w);
  float o7 = fmaxf(acc[7] + bb.w, 0.f) + bfhi(hp.w);
  uint4 ov;
  ov.x = (unsigned)f2bf(o0) | ((unsigned)f2bf(o1) << 16);
  ov.y = (unsigned)f2bf(o2) | ((unsigned)f2bf(o3) << 16);
  ov.z = (unsigned)f2bf(o4) | ((unsigned)f2bf(o5) << 16);
  ov.w = (unsigned)f2bf(o6) | ((unsigned)f2bf(o7) << 16);
  ((uint4*)houtb)[(size_t)n * 16 + lane] = ov;
}

// ---------------- fused pooling + head: one 1024-thread block per graph ----------------
__launch_bounds__(1024)
__global__ void k_poolhead(const unsigned short* __restrict__ hb, const int* __restrict__ goffs,
                           const float* __restrict__ mf,
                           const float* __restrict__ Wm, const float* __restrict__ bm,
                           const float* __restrict__ gamma, const float* __restrict__ beta,
                           const float* __restrict__ W1, const float* __restrict__ b1,
                           const float* __restrict__ W2, const float* __restrict__ b2,
                           float* __restrict__ out) {
  __shared__ float4 smax[32][32];   // [slot][lane]
  __shared__ float4 ssum[32][32];
  __shared__ float z[288];
  __shared__ float z1[128];
  int g = blockIdx.x;
  int slot = threadIdx.x >> 5;
  int lane = threadIdx.x & 31;
  int a = goffs[g], bnd = goffs[g + 1];
  const uint2* hb2 = (const uint2*)hb;

  float4 mx = make_float4(-INFINITY, -INFINITY, -INFINITY, -INFINITY);
  float4 sm = make_float4(0.f, 0.f, 0.f, 0.f);
  for (int i = a + slot; i < bnd; i += 32) {
    uint2 p = hb2[(size_t)i * 32 + lane];
    float4 v = make_float4(bflo(p.x), bfhi(p.x), bflo(p.y), bfhi(p.y));
    MAX4(mx, v);
    ADD4(sm, v);
  }
  smax[slot][lane] = mx;
  ssum[slot][lane] = sm;
  __syncthreads();
#pragma unroll
  for (int off = 16; off >= 1; off >>= 1) {
    if (slot < off) {
      float4 m2 = smax[slot + off][lane];
      float4 s2 = ssum[slot + off][lane];
      float4 m1 = smax[slot][lane];
      float4 s1 = ssum[slot][lane];
      MAX4(m1, m2);
      ADD4(s1, s2);
      smax[slot][lane] = m1;
      ssum[slot][lane] = s1;
    }
    __syncthreads();
  }
  if (slot == 0) {
    *(float4*)&z[lane * 4]       = smax[0][lane];
    *(float4*)&z[128 + lane * 4] = ssum[0][lane];
  }
  if (threadIdx.x < NMH) {
    int t = threadIdx.x;
    float acc = bm[t];
    for (int k = 0; k < NM; ++k) acc += mf[g * NM + k] * Wm[k * NMH + t];
    acc = acc * gamma[t] + beta[t];
    z[256 + t] = fmaxf(acc, 0.f);
  }
  __syncthreads();
  if (threadIdx.x < 128) {
    int t = threadIdx.x;
    float acc = b1[t];
    for (int k = 0; k < 288; ++k) acc += z[k] * W1[k * HD + t];
    z1[t] = fmaxf(acc, 0.f);
  }
  __syncthreads();
  if (threadIdx.x < NO) {
    int t = threadIdx.x;
    float a2 = b2[t];
    for (int k = 0; k < HD; ++k) a2 += z1[k] * W2[k * NO + t];
    out[g * NO + t] = a2;
  }
}

extern "C" void kernel_launch(void* const* d_in, const int* in_sizes, int n_in,
                              void* d_out, int out_size, void* d_ws, size_t ws_size,
                              hipStream_t stream) {
  const float* x     = (const float*)d_in[0];
  const int*   eidx  = (const int*)d_in[1];
  const int*   batch = (const int*)d_in[2];
  const float* mf    = (const float*)d_in[3];
  const float* Ws    = (const float*)d_in[4];
  const float* bs    = (const float*)d_in[5];
  const float* Wm    = (const float*)d_in[6];
  const float* bm    = (const float*)d_in[7];
  const float* gamma = (const float*)d_in[8];
  const float* beta  = (const float*)d_in[9];
  const float* W1    = (const float*)d_in[10];
  const float* b1    = (const float*)d_in[11];
  const float* W2    = (const float*)d_in[12];
  const float* b2    = (const float*)d_in[13];
  float* out = (float*)d_out;

  const int* src = eidx;
  const int* dst = eidx + NE;

  // workspace carve-out
  char* w = (char*)d_ws;
  size_t off = 0;
  auto alloc = [&](size_t bytes) -> void* {
    void* p = w + off;
    off += (bytes + 255) & ~(size_t)255;
    return p;
  };
  float* dis    = (float*)alloc((size_t)NN * 4);
  unsigned short* xw  = (unsigned short*)alloc((size_t)NN * HD * 2);  // bf16 GEMM out
  unsigned short* xbf = (unsigned short*)alloc((size_t)NN * HD * 2);  // bf16 copy of x
  unsigned short* hbf = (unsigned short*)alloc((size_t)NN * HD * 2);  // bf16 h state
  unsigned short* wT  = (unsigned short*)alloc((size_t)NL * HD * HD * 2);
  int* counts   = (int*)alloc((size_t)NN * 4);        // degree
  int* cur      = (int*)alloc((size_t)NN * 4);        // fill cursor (adjacent to counts)
  unsigned* csr = (unsigned*)alloc((size_t)NN * CST * 4);
  int* goffs    = (int*)alloc((size_t)(NB + 1) * 4);
  (void)ws_size;

  // one memset covers counts + cur (adjacent carve-outs)
  size_t zspan = (size_t)((char*)(cur + NN) - (char*)counts);
  hipMemsetAsync(counts, 0, zspan, stream);

  k_hist<<<(NE / 4 + 255) / 256, 256, 0, stream>>>((const int4*)dst, counts);
  k_setup<<<(NT_ALL + 255) / 256, 256, 0, stream>>>((const float4*)x, (ushort4*)xbf,
                                                    Ws, wT, batch, goffs, counts, dis);
  k_fill<<<(NE + 255) / 256, 256, 0, stream>>>(src, dst, dis, cur, csr);

  for (int l = 0; l < NL; ++l) {
    const unsigned short* gin_bf = (l == 0) ? xbf : hbf;
    k_gemm_mfma<<<(NN + 127) / 128, 256, 0, stream>>>(gin_bf, wT + (size_t)l * HD * HD, xw);
    k_agg16<<<(NN + 15) / 16, 256, 0, stream>>>(xw, dis, counts, csr, bs + (size_t)l * HD, gin_bf, hbf);
  }

  k_poolhead<<<NB, 1024, 0, stream>>>(hbf, goffs, mf, Wm, bm, gamma, beta, W1, b1, W2, b2, out);
}